// Round 1
// baseline (722.120 us; speedup 1.0000x reference)
//
#include <hip/hip_runtime.h>

#define NN 100000
#define NE 1200000
#define DD 64

// ---------------- degree / norm ----------------

__global__ void init_deg(float* __restrict__ deg, int n) {
    int i = blockIdx.x * blockDim.x + threadIdx.x;
    if (i < n) deg[i] = 1.0f;   // self-loop weight
}

__global__ void acc_deg(const int* __restrict__ dst, const float* __restrict__ ew,
                        float* __restrict__ deg, int ne) {
    int i = blockIdx.x * blockDim.x + threadIdx.x;
    if (i < ne) atomicAdd(&deg[dst[i]], ew[i]);
}

__global__ void finish_dis(float* __restrict__ deg, int n) {
    int i = blockIdx.x * blockDim.x + threadIdx.x;
    if (i < n) {
        float d = deg[i];
        deg[i] = d > 0.0f ? rsqrtf(d) : 0.0f;   // deg >= 1 always, but match ref
    }
}

// ---------------- GEMM h = x@W, acc = b + dis^2 * h ----------------
// Block: 256 threads, 64 rows x 64 cols. W (16KB) + padded X tile (17KB) in LDS.
// Thread computes 4 rows x 4 cols. Xs padded to stride 68 -> broadcast-friendly reads.

__global__ __launch_bounds__(256) void gemm_init(
    const float* __restrict__ x, const float* __restrict__ W,
    const float* __restrict__ b, const float* __restrict__ dis,
    float* __restrict__ h, float* __restrict__ acc, int n)
{
    __shared__ float Ws[64 * 64];
    __shared__ float Xs[64 * 68];   // pad 68: bank-friendly, keeps float4 alignment

    const int t  = threadIdx.x;
    const int r0 = blockIdx.x * 64;
    const int rows = min(64, n - r0);

    // load W: contiguous 4096 floats
    {
        const float4* W4 = (const float4*)W;
        float4* Ws4 = (float4*)Ws;
        #pragma unroll
        for (int k = 0; k < 4; ++k) Ws4[t + 256 * k] = W4[t + 256 * k];
    }
    // load X tile (contiguous in global) -> padded LDS rows
    {
        const float4* X4 = (const float4*)(x + (size_t)r0 * DD);
        const int nf4 = rows * 16;
        #pragma unroll
        for (int k = 0; k < 4; ++k) {
            int idx = t + 256 * k;           // float4 index; row = idx>>4, c4 = (idx&15)*4
            float4 v = make_float4(0.f, 0.f, 0.f, 0.f);
            if (idx < nf4) v = X4[idx];
            int row = idx >> 4, c4 = (idx & 15) * 4;
            *(float4*)&Xs[row * 68 + c4] = v;
        }
    }
    __syncthreads();

    const int row0 = (t >> 4) * 4;      // 0,4,8,12 within wave -> broadcast reads
    const int col0 = (t & 15) * 4;

    float a[4][4];
    #pragma unroll
    for (int i = 0; i < 4; ++i)
        #pragma unroll
        for (int j = 0; j < 4; ++j) a[i][j] = 0.f;

    #pragma unroll 4
    for (int j = 0; j < 64; ++j) {
        float4 wv = *(const float4*)&Ws[j * 64 + col0];
        float xr[4];
        #pragma unroll
        for (int i = 0; i < 4; ++i) xr[i] = Xs[(row0 + i) * 68 + j];
        #pragma unroll
        for (int i = 0; i < 4; ++i) {
            a[i][0] = fmaf(xr[i], wv.x, a[i][0]);
            a[i][1] = fmaf(xr[i], wv.y, a[i][1]);
            a[i][2] = fmaf(xr[i], wv.z, a[i][2]);
            a[i][3] = fmaf(xr[i], wv.w, a[i][3]);
        }
    }

    float4 bv = *(const float4*)&b[col0];
    #pragma unroll
    for (int i = 0; i < 4; ++i) {
        int r = r0 + row0 + i;
        if (r < n) {
            float4 hv = make_float4(a[i][0], a[i][1], a[i][2], a[i][3]);
            *(float4*)&h[(size_t)r * DD + col0] = hv;
            float di = dis[r];
            float d2 = di * di;
            float4 av = make_float4(fmaf(d2, hv.x, bv.x), fmaf(d2, hv.y, bv.y),
                                    fmaf(d2, hv.z, bv.z), fmaf(d2, hv.w, bv.w));
            *(float4*)&acc[(size_t)r * DD + col0] = av;
        }
    }
}

// ---------------- edge scatter: one wave per edge, lane = channel ----------------

__global__ __launch_bounds__(256) void scatter_edges(
    const int* __restrict__ src, const int* __restrict__ dst,
    const float* __restrict__ ew, const float* __restrict__ dis,
    const float* __restrict__ h, float* __restrict__ acc, int ne)
{
    const int lane = threadIdx.x & 63;
    const int wave = blockIdx.x * (blockDim.x >> 6) + (threadIdx.x >> 6);
    const int nw   = gridDim.x * (blockDim.x >> 6);
    for (int e = wave; e < ne; e += nw) {
        int s = src[e];
        int d = dst[e];
        float norm = dis[s] * ew[e] * dis[d];
        float v = norm * h[(size_t)s * DD + lane];
        atomicAdd(&acc[(size_t)d * DD + lane], v);
    }
}

// ---------------- elementwise epilogues ----------------

__global__ void relu_copy(const float* __restrict__ acc, float* __restrict__ out, int n4) {
    int i = blockIdx.x * blockDim.x + threadIdx.x;
    if (i < n4) {
        float4 v = ((const float4*)acc)[i];
        v.x = fmaxf(v.x, 0.f); v.y = fmaxf(v.y, 0.f);
        v.z = fmaxf(v.z, 0.f); v.w = fmaxf(v.w, 0.f);
        ((float4*)out)[i] = v;
    }
}

__global__ void final_combine(const float* __restrict__ acc, float* __restrict__ out, int n4) {
    int i = blockIdx.x * blockDim.x + threadIdx.x;
    if (i < n4) {
        float4 v = ((const float4*)acc)[i];   // pre-relu layer2
        float4 x1 = ((const float4*)out)[i];  // relu'd layer1
        float4 r;
        r.x = 0.5f * (x1.x + fmaxf(v.x, 0.f));
        r.y = 0.5f * (x1.y + fmaxf(v.y, 0.f));
        r.z = 0.5f * (x1.z + fmaxf(v.z, 0.f));
        r.w = 0.5f * (x1.w + fmaxf(v.w, 0.f));
        ((float4*)out)[i] = r;
    }
}

// ---------------- launch ----------------

extern "C" void kernel_launch(void* const* d_in, const int* in_sizes, int n_in,
                              void* d_out, int out_size, void* d_ws, size_t ws_size,
                              hipStream_t stream) {
    const float* x   = (const float*)d_in[0];
    const int*   ei  = (const int*)d_in[1];     // [2, NE] flattened: src then dst
    const float* ewt = (const float*)d_in[2];
    const float* W1  = (const float*)d_in[3];
    const float* b1  = (const float*)d_in[4];
    const float* W2  = (const float*)d_in[5];
    const float* b2  = (const float*)d_in[6];
    float* out = (float*)d_out;

    const int* srcv = ei;
    const int* dstv = ei + NE;

    // workspace: dis (N, padded) | h (N*64) | acc (N*64)  ~= 52 MB
    float* dis = (float*)d_ws;
    float* h   = dis + 131072;
    float* acc = h + (size_t)NN * DD;

    const int n4 = NN * DD / 4;   // 1.6M float4s

    // norm precompute (graph shared by both layers)
    init_deg<<<(NN + 255) / 256, 256, 0, stream>>>(dis, NN);
    acc_deg<<<(NE + 255) / 256, 256, 0, stream>>>(dstv, ewt, dis, NE);
    finish_dis<<<(NN + 255) / 256, 256, 0, stream>>>(dis, NN);

    // layer 1
    gemm_init<<<(NN + 63) / 64, 256, 0, stream>>>(x, W1, b1, dis, h, acc, NN);
    scatter_edges<<<2048, 256, 0, stream>>>(srcv, dstv, ewt, dis, h, acc, NE);
    relu_copy<<<(n4 + 255) / 256, 256, 0, stream>>>(acc, out, n4);   // x1 -> d_out

    // layer 2 (input = x1 in d_out)
    gemm_init<<<(NN + 63) / 64, 256, 0, stream>>>(out, W2, b2, dis, h, acc, NN);
    scatter_edges<<<2048, 256, 0, stream>>>(srcv, dstv, ewt, dis, h, acc, NE);
    final_combine<<<(n4 + 255) / 256, 256, 0, stream>>>(acc, out, n4);
}

// Round 2
// 448.995 us; speedup vs baseline: 1.6083x; 1.6083x over previous
//
#include <hip/hip_runtime.h>

#define NN 100000
#define NE 1200000
#define DD 64

// ======================= degree/norm + CSR build =======================

__global__ void init_arrays(float* __restrict__ deg, int* __restrict__ counts,
                            int* __restrict__ cursor, int n) {
    int i = blockIdx.x * blockDim.x + threadIdx.x;
    if (i < n) { deg[i] = 1.0f; counts[i] = 0; cursor[i] = 0; }
}

__global__ void hist_deg(const int* __restrict__ dst, const float* __restrict__ ew,
                         float* __restrict__ deg, int* __restrict__ counts, int ne) {
    int i = blockIdx.x * blockDim.x + threadIdx.x;
    if (i < ne) {
        int d = dst[i];
        atomicAdd(&deg[d], ew[i]);
        atomicAdd(&counts[d], 1);
    }
}

__global__ void finish_dis(float* __restrict__ deg, int n) {
    int i = blockIdx.x * blockDim.x + threadIdx.x;
    if (i < n) {
        float d = deg[i];
        deg[i] = d > 0.0f ? rsqrtf(d) : 0.0f;
    }
}

// ---- two-level exclusive scan (512-wide blocks) ----

__global__ __launch_bounds__(512) void scan_block(const int* __restrict__ in,
                                                  int* __restrict__ out,
                                                  int* __restrict__ bsums, int n) {
    __shared__ int s[512];
    int t = threadIdx.x;
    int i = blockIdx.x * 512 + t;
    int v = (i < n) ? in[i] : 0;
    s[t] = v;
    __syncthreads();
    for (int off = 1; off < 512; off <<= 1) {
        int add = (t >= off) ? s[t - off] : 0;
        __syncthreads();
        s[t] += add;
        __syncthreads();
    }
    if (i < n) out[i] = s[t] - v;          // exclusive
    if (bsums && t == 511) bsums[blockIdx.x] = s[511];
}

__global__ __launch_bounds__(512) void scan_add(int* __restrict__ rowptr,
                                                const int* __restrict__ bsums, int n) {
    int i = blockIdx.x * 512 + threadIdx.x;
    if (i < n) rowptr[i] += bsums[blockIdx.x];
    if (i == 0) rowptr[n] = NE;            // sentinel
}

__global__ void reorder_edges(const int* __restrict__ src, const int* __restrict__ dst,
                              const float* __restrict__ ew, const float* __restrict__ dis,
                              const int* __restrict__ rowptr, int* __restrict__ cursor,
                              int* __restrict__ csr_src, float* __restrict__ csr_norm, int ne) {
    int e = blockIdx.x * blockDim.x + threadIdx.x;
    if (e < ne) {
        int s = src[e], d = dst[e];
        int pos = rowptr[d] + atomicAdd(&cursor[d], 1);
        csr_src[pos] = s;
        csr_norm[pos] = dis[s] * ew[e] * dis[d];
    }
}

// ======================= GEMM h = x@W =======================
// 256 threads, 64x64 tile; W + padded X tile in LDS; 4x4 per thread.

__global__ __launch_bounds__(256) void gemm_h(
    const float* __restrict__ x, const float* __restrict__ W,
    float* __restrict__ h, int n)
{
    __shared__ float Ws[64 * 64];
    __shared__ float Xs[64 * 68];

    const int t  = threadIdx.x;
    const int r0 = blockIdx.x * 64;
    const int rows = min(64, n - r0);

    {
        const float4* W4 = (const float4*)W;
        float4* Ws4 = (float4*)Ws;
        #pragma unroll
        for (int k = 0; k < 4; ++k) Ws4[t + 256 * k] = W4[t + 256 * k];
    }
    {
        const float4* X4 = (const float4*)(x + (size_t)r0 * DD);
        const int nf4 = rows * 16;
        #pragma unroll
        for (int k = 0; k < 4; ++k) {
            int idx = t + 256 * k;
            float4 v = make_float4(0.f, 0.f, 0.f, 0.f);
            if (idx < nf4) v = X4[idx];
            int row = idx >> 4, c4 = (idx & 15) * 4;
            *(float4*)&Xs[row * 68 + c4] = v;
        }
    }
    __syncthreads();

    const int row0 = (t >> 4) * 4;
    const int col0 = (t & 15) * 4;

    float a[4][4];
    #pragma unroll
    for (int i = 0; i < 4; ++i)
        #pragma unroll
        for (int j = 0; j < 4; ++j) a[i][j] = 0.f;

    #pragma unroll 4
    for (int j = 0; j < 64; ++j) {
        float4 wv = *(const float4*)&Ws[j * 64 + col0];
        float xr[4];
        #pragma unroll
        for (int i = 0; i < 4; ++i) xr[i] = Xs[(row0 + i) * 68 + j];
        #pragma unroll
        for (int i = 0; i < 4; ++i) {
            a[i][0] = fmaf(xr[i], wv.x, a[i][0]);
            a[i][1] = fmaf(xr[i], wv.y, a[i][1]);
            a[i][2] = fmaf(xr[i], wv.z, a[i][2]);
            a[i][3] = fmaf(xr[i], wv.w, a[i][3]);
        }
    }

    #pragma unroll
    for (int i = 0; i < 4; ++i) {
        int r = r0 + row0 + i;
        if (r < n)
            *(float4*)&h[(size_t)r * DD + col0] =
                make_float4(a[i][0], a[i][1], a[i][2], a[i][3]);
    }
}

// ======================= CSR gather (one wave per node) =======================
// acc = b[lane] + dis[n]^2 * h[n] + sum_e norm[e] * h[src[e]]
// FINAL=false: out = relu(acc)           (layer 1 -> x1)
// FINAL=true : out = 0.5*(prev + relu(acc))

template <bool FINAL>
__global__ __launch_bounds__(256) void gather_csr(
    const float* __restrict__ h, const float* __restrict__ b,
    const float* __restrict__ dis, const int* __restrict__ rowptr,
    const int* __restrict__ csr_src, const float* __restrict__ csr_norm,
    const float* __restrict__ prev, float* __restrict__ out)
{
    const int node = (blockIdx.x * blockDim.x + threadIdx.x) >> 6;
    const int lane = threadIdx.x & 63;
    if (node >= NN) return;

    const float di = dis[node];
    float a0 = fmaf(di * di, h[node * DD + lane], b[lane]);
    float a1 = 0.f;

    int j   = rowptr[node];
    int end = rowptr[node + 1];
    for (; j + 1 < end; j += 2) {
        int   s0 = csr_src[j],     s1 = csr_src[j + 1];
        float n0 = csr_norm[j],    n1 = csr_norm[j + 1];
        a0 = fmaf(n0, h[s0 * DD + lane], a0);
        a1 = fmaf(n1, h[s1 * DD + lane], a1);
    }
    if (j < end)
        a0 = fmaf(csr_norm[j], h[csr_src[j] * DD + lane], a0);

    float v = fmaxf(a0 + a1, 0.f);
    int idx = node * DD + lane;
    if (FINAL) out[idx] = 0.5f * (prev[idx] + v);
    else       out[idx] = v;
}

// ======================= launch =======================

extern "C" void kernel_launch(void* const* d_in, const int* in_sizes, int n_in,
                              void* d_out, int out_size, void* d_ws, size_t ws_size,
                              hipStream_t stream) {
    const float* x   = (const float*)d_in[0];
    const int*   ei  = (const int*)d_in[1];
    const float* ewt = (const float*)d_in[2];
    const float* W1  = (const float*)d_in[3];
    const float* b1  = (const float*)d_in[4];
    const float* W2  = (const float*)d_in[5];
    const float* b2  = (const float*)d_in[6];
    float* out = (float*)d_out;

    const int* srcv = ei;
    const int* dstv = ei + NE;

    // workspace layout (4B units, padded)
    float* dis      = (float*)d_ws;            // 102400
    int*   counts   = (int*)(dis + 102400);    // 102400
    int*   cursor   = counts + 102400;         // 102400
    int*   rowptr   = cursor + 102400;         // 102400 (NN+1 used)
    int*   bsums    = rowptr + 102400;         // 1024
    int*   csr_src  = bsums + 1024;            // NE
    float* csr_norm = (float*)(csr_src + NE);  // NE
    float* h        = csr_norm + NE;           // NN*64

    const int NB_N  = (NN + 255) / 256;
    const int NB_E  = (NE + 255) / 256;
    const int NB_S  = (NN + 511) / 512;        // 196 scan blocks

    // --- norm + CSR (graph shared by both layers) ---
    init_arrays<<<NB_N, 256, 0, stream>>>(dis, counts, cursor, NN);
    hist_deg<<<NB_E, 256, 0, stream>>>(dstv, ewt, dis, counts, NE);
    finish_dis<<<NB_N, 256, 0, stream>>>(dis, NN);
    scan_block<<<NB_S, 512, 0, stream>>>(counts, rowptr, bsums, NN);
    scan_block<<<1, 512, 0, stream>>>(bsums, bsums, nullptr, NB_S);
    scan_add<<<NB_S, 512, 0, stream>>>(rowptr, bsums, NN);
    reorder_edges<<<NB_E, 256, 0, stream>>>(srcv, dstv, ewt, dis, rowptr, cursor,
                                            csr_src, csr_norm, NE);

    const int GB = (NN * 64 + 255) / 256;      // one wave per node

    // --- layer 1 ---
    gemm_h<<<(NN + 63) / 64, 256, 0, stream>>>(x, W1, h, NN);
    gather_csr<false><<<GB, 256, 0, stream>>>(h, b1, dis, rowptr, csr_src, csr_norm,
                                              nullptr, out);
    // --- layer 2 (input = x1 in d_out) ---
    gemm_h<<<(NN + 63) / 64, 256, 0, stream>>>(out, W2, h, NN);
    gather_csr<true><<<GB, 256, 0, stream>>>(h, b2, dis, rowptr, csr_src, csr_norm,
                                             out, out);
}

// Round 3
// 377.101 us; speedup vs baseline: 1.9149x; 1.1906x over previous
//
#include <hip/hip_runtime.h>

#define NN 100000
#define NE 1200000
#define DD 64

#define FIX_SCALE 1099511627776.0f   // 2^40
#define FIX_INV   (1.0 / 1099511627776.0)

// ======================= packed histogram =======================
// packed[d]: bits[48:63] = incoming-edge count, bits[0:47] = sum(ew) in 2^-40 fixed point.
// atomicAdd's returned old count = this edge's rank within its dst segment.

__global__ void init_packed(unsigned long long* __restrict__ packed, int n) {
    int i = blockIdx.x * blockDim.x + threadIdx.x;
    if (i < n) packed[i] = 0ull;
}

__global__ void hist64(const int* __restrict__ dst, const float* __restrict__ ew,
                       unsigned long long* __restrict__ packed,
                       int* __restrict__ rank, int ne) {
    int i = blockIdx.x * blockDim.x + threadIdx.x;
    if (i < ne) {
        int d = dst[i];
        unsigned long long inc =
            (1ull << 48) | (unsigned long long)(ew[i] * FIX_SCALE);
        unsigned long long old = atomicAdd(&packed[d], inc);
        rank[i] = (int)(old >> 48);
    }
}

__global__ void finish_unpack(const unsigned long long* __restrict__ packed,
                              int* __restrict__ counts, float* __restrict__ dis, int n) {
    int i = blockIdx.x * blockDim.x + threadIdx.x;
    if (i < n) {
        unsigned long long p = packed[i];
        counts[i] = (int)(p >> 48);
        float deg = 1.0f + (float)((double)(p & ((1ull << 48) - 1)) * FIX_INV);
        dis[i] = rsqrtf(deg);   // deg >= 1 always
    }
}

// ---- two-level exclusive scan (512-wide blocks) ----

__global__ __launch_bounds__(512) void scan_block(const int* __restrict__ in,
                                                  int* __restrict__ out,
                                                  int* __restrict__ bsums, int n) {
    __shared__ int s[512];
    int t = threadIdx.x;
    int i = blockIdx.x * 512 + t;
    int v = (i < n) ? in[i] : 0;
    s[t] = v;
    __syncthreads();
    for (int off = 1; off < 512; off <<= 1) {
        int add = (t >= off) ? s[t - off] : 0;
        __syncthreads();
        s[t] += add;
        __syncthreads();
    }
    if (i < n) out[i] = s[t] - v;          // exclusive
    if (bsums && t == 511) bsums[blockIdx.x] = s[511];
}

__global__ __launch_bounds__(512) void scan_add(int* __restrict__ rowptr,
                                                const int* __restrict__ bsums, int n) {
    int i = blockIdx.x * 512 + threadIdx.x;
    if (i < n) rowptr[i] += bsums[blockIdx.x];
    if (i == 0) rowptr[n] = NE;            // sentinel
}

// ---- atomic-free reorder: pos = rowptr[d] + rank[e] ----

__global__ void reorder_edges(const int* __restrict__ src, const int* __restrict__ dst,
                              const float* __restrict__ ew, const float* __restrict__ dis,
                              const int* __restrict__ rowptr, const int* __restrict__ rank,
                              int* __restrict__ csr_src, float* __restrict__ csr_norm, int ne) {
    int e = blockIdx.x * blockDim.x + threadIdx.x;
    if (e < ne) {
        int s = src[e], d = dst[e];
        int pos = rowptr[d] + rank[e];
        csr_src[pos] = s;
        csr_norm[pos] = dis[s] * ew[e] * dis[d];
    }
}

// ======================= GEMM h = x@W =======================

__global__ __launch_bounds__(256) void gemm_h(
    const float* __restrict__ x, const float* __restrict__ W,
    float* __restrict__ h, int n)
{
    __shared__ float Ws[64 * 64];
    __shared__ float Xs[64 * 68];

    const int t  = threadIdx.x;
    const int r0 = blockIdx.x * 64;
    const int rows = min(64, n - r0);

    {
        const float4* W4 = (const float4*)W;
        float4* Ws4 = (float4*)Ws;
        #pragma unroll
        for (int k = 0; k < 4; ++k) Ws4[t + 256 * k] = W4[t + 256 * k];
    }
    {
        const float4* X4 = (const float4*)(x + (size_t)r0 * DD);
        const int nf4 = rows * 16;
        #pragma unroll
        for (int k = 0; k < 4; ++k) {
            int idx = t + 256 * k;
            float4 v = make_float4(0.f, 0.f, 0.f, 0.f);
            if (idx < nf4) v = X4[idx];
            int row = idx >> 4, c4 = (idx & 15) * 4;
            *(float4*)&Xs[row * 68 + c4] = v;
        }
    }
    __syncthreads();

    const int row0 = (t >> 4) * 4;
    const int col0 = (t & 15) * 4;

    float a[4][4];
    #pragma unroll
    for (int i = 0; i < 4; ++i)
        #pragma unroll
        for (int j = 0; j < 4; ++j) a[i][j] = 0.f;

    #pragma unroll 4
    for (int j = 0; j < 64; ++j) {
        float4 wv = *(const float4*)&Ws[j * 64 + col0];
        float xr[4];
        #pragma unroll
        for (int i = 0; i < 4; ++i) xr[i] = Xs[(row0 + i) * 68 + j];
        #pragma unroll
        for (int i = 0; i < 4; ++i) {
            a[i][0] = fmaf(xr[i], wv.x, a[i][0]);
            a[i][1] = fmaf(xr[i], wv.y, a[i][1]);
            a[i][2] = fmaf(xr[i], wv.z, a[i][2]);
            a[i][3] = fmaf(xr[i], wv.w, a[i][3]);
        }
    }

    #pragma unroll
    for (int i = 0; i < 4; ++i) {
        int r = r0 + row0 + i;
        if (r < n)
            *(float4*)&h[(size_t)r * DD + col0] =
                make_float4(a[i][0], a[i][1], a[i][2], a[i][3]);
    }
}

// ======================= CSR gather (one wave per node) =======================

template <bool FINAL>
__global__ __launch_bounds__(256) void gather_csr(
    const float* __restrict__ h, const float* __restrict__ b,
    const float* __restrict__ dis, const int* __restrict__ rowptr,
    const int* __restrict__ csr_src, const float* __restrict__ csr_norm,
    const float* __restrict__ prev, float* __restrict__ out)
{
    const int node = (blockIdx.x * blockDim.x + threadIdx.x) >> 6;
    const int lane = threadIdx.x & 63;
    if (node >= NN) return;

    const float di = dis[node];
    float a0 = fmaf(di * di, h[node * DD + lane], b[lane]);
    float a1 = 0.f;

    int j   = rowptr[node];
    int end = rowptr[node + 1];
    for (; j + 1 < end; j += 2) {
        int   s0 = csr_src[j],  s1 = csr_src[j + 1];
        float n0 = csr_norm[j], n1 = csr_norm[j + 1];
        a0 = fmaf(n0, h[s0 * DD + lane], a0);
        a1 = fmaf(n1, h[s1 * DD + lane], a1);
    }
    if (j < end)
        a0 = fmaf(csr_norm[j], h[csr_src[j] * DD + lane], a0);

    float v = fmaxf(a0 + a1, 0.f);
    int idx = node * DD + lane;
    if (FINAL) out[idx] = 0.5f * (prev[idx] + v);
    else       out[idx] = v;
}

// ======================= launch =======================

extern "C" void kernel_launch(void* const* d_in, const int* in_sizes, int n_in,
                              void* d_out, int out_size, void* d_ws, size_t ws_size,
                              hipStream_t stream) {
    const float* x   = (const float*)d_in[0];
    const int*   ei  = (const int*)d_in[1];
    const float* ewt = (const float*)d_in[2];
    const float* W1  = (const float*)d_in[3];
    const float* b1  = (const float*)d_in[4];
    const float* W2  = (const float*)d_in[5];
    const float* b2  = (const float*)d_in[6];
    float* out = (float*)d_out;

    const int* srcv = ei;
    const int* dstv = ei + NE;

    // workspace layout (4B units; packed needs 8B alignment -> first)
    unsigned long long* packed = (unsigned long long*)d_ws;   // 100000 u64 = 200000 slots
    float* dis      = (float*)d_ws + 204800;
    int*   counts   = (int*)((float*)d_ws + 204800 + 102400);
    int*   rowptr   = counts + 102400;         // NN+1 used
    int*   bsums    = rowptr + 102400;         // 1024
    int*   rank     = bsums + 1024;            // NE
    int*   csr_src  = rank + NE;               // NE
    float* csr_norm = (float*)(csr_src + NE);  // NE
    float* h        = csr_norm + NE;           // NN*64

    const int NB_N = (NN + 255) / 256;
    const int NB_E = (NE + 255) / 256;
    const int NB_S = (NN + 511) / 512;

    // --- norm + CSR (graph shared by both layers) ---
    init_packed<<<NB_N, 256, 0, stream>>>(packed, NN);
    hist64<<<NB_E, 256, 0, stream>>>(dstv, ewt, packed, rank, NE);
    finish_unpack<<<NB_N, 256, 0, stream>>>(packed, counts, dis, NN);
    scan_block<<<NB_S, 512, 0, stream>>>(counts, rowptr, bsums, NN);
    scan_block<<<1, 512, 0, stream>>>(bsums, bsums, nullptr, NB_S);
    scan_add<<<NB_S, 512, 0, stream>>>(rowptr, bsums, NN);
    reorder_edges<<<NB_E, 256, 0, stream>>>(srcv, dstv, ewt, dis, rowptr, rank,
                                            csr_src, csr_norm, NE);

    const int GB = (NN * 64 + 255) / 256;      // one wave per node

    // --- layer 1 ---
    gemm_h<<<(NN + 63) / 64, 256, 0, stream>>>(x, W1, h, NN);
    gather_csr<false><<<GB, 256, 0, stream>>>(h, b1, dis, rowptr, csr_src, csr_norm,
                                              nullptr, out);
    // --- layer 2 (input = x1 in d_out) ---
    gemm_h<<<(NN + 63) / 64, 256, 0, stream>>>(out, W2, h, NN);
    gather_csr<true><<<GB, 256, 0, stream>>>(h, b2, dis, rowptr, csr_src, csr_norm,
                                             out, out);
}

// Round 4
// 298.628 us; speedup vs baseline: 2.4181x; 1.2628x over previous
//
#include <hip/hip_runtime.h>

#define NN 100000
#define NE 1200000
#define DD 64

#define FIX_SCALE 1099511627776.0f   // 2^40
#define FIX_INV   (1.0 / 1099511627776.0)

static __device__ __forceinline__ unsigned short f2bf(float f) {
    unsigned int u = __float_as_uint(f);
    unsigned int r = (u + 0x7fffu + ((u >> 16) & 1u)) >> 16;   // RNE
    return (unsigned short)r;
}
static __device__ __forceinline__ float bf2f(unsigned short s) {
    return __uint_as_float(((unsigned int)s) << 16);
}

// ======================= packed histogram =======================
// packed[d]: bits[48:63] = count, bits[0:47] = sum(ew) in 2^-40 fixed point.
// Returned old count = edge's rank within its dst segment (atomic-free reorder).

__global__ void init_packed(unsigned long long* __restrict__ packed, int n) {
    int i = blockIdx.x * blockDim.x + threadIdx.x;
    if (i < n) packed[i] = 0ull;
}

__global__ void hist64(const int* __restrict__ dst, const float* __restrict__ ew,
                       unsigned long long* __restrict__ packed,
                       int* __restrict__ rank, int ne) {
    int i = blockIdx.x * blockDim.x + threadIdx.x;
    if (i < ne) {
        int d = dst[i];
        unsigned long long inc =
            (1ull << 48) | (unsigned long long)(ew[i] * FIX_SCALE);
        unsigned long long old = atomicAdd(&packed[d], inc);
        rank[i] = (int)(old >> 48);
    }
}

// ---- scan level 1 fused with dis computation: reads packed directly ----

__global__ __launch_bounds__(512) void scan_packed(
    const unsigned long long* __restrict__ packed,
    int* __restrict__ rowptr, int* __restrict__ bsums,
    float* __restrict__ dis, int n)
{
    __shared__ int s[512];
    int t = threadIdx.x;
    int i = blockIdx.x * 512 + t;
    int v = 0;
    if (i < n) {
        unsigned long long p = packed[i];
        v = (int)(p >> 48);
        float deg = 1.0f + (float)((double)(p & ((1ull << 48) - 1)) * FIX_INV);
        dis[i] = rsqrtf(deg);
    }
    s[t] = v;
    __syncthreads();
    for (int off = 1; off < 512; off <<= 1) {
        int add = (t >= off) ? s[t - off] : 0;
        __syncthreads();
        s[t] += add;
        __syncthreads();
    }
    if (i < n) rowptr[i] = s[t] - v;       // exclusive
    if (t == 511) bsums[blockIdx.x] = s[511];
}

__global__ __launch_bounds__(512) void scan_block(const int* __restrict__ in,
                                                  int* __restrict__ out,
                                                  int n) {
    __shared__ int s[512];
    int t = threadIdx.x;
    int v = (t < n) ? in[t] : 0;
    s[t] = v;
    __syncthreads();
    for (int off = 1; off < 512; off <<= 1) {
        int add = (t >= off) ? s[t - off] : 0;
        __syncthreads();
        s[t] += add;
        __syncthreads();
    }
    if (t < n) out[t] = s[t] - v;
}

__global__ __launch_bounds__(512) void scan_add(int* __restrict__ rowptr,
                                                const int* __restrict__ bsums, int n) {
    int i = blockIdx.x * 512 + threadIdx.x;
    if (i < n) rowptr[i] += bsums[blockIdx.x];
    if (i == 0) rowptr[n] = NE;            // sentinel
}

// ---- atomic-free reorder: csr[rowptr[d] + rank[e]] = {src, norm} ----

__global__ void reorder_edges(const int* __restrict__ src, const int* __restrict__ dst,
                              const float* __restrict__ ew, const float* __restrict__ dis,
                              const int* __restrict__ rowptr, const int* __restrict__ rank,
                              int2* __restrict__ csr, int ne) {
    int e = blockIdx.x * blockDim.x + threadIdx.x;
    if (e < ne) {
        int s = src[e], d = dst[e];
        int pos = rowptr[d] + rank[e];
        float norm = dis[s] * ew[e] * dis[d];
        csr[pos] = make_int2(s, __float_as_int(norm));
    }
}

// ======================= GEMM h = x@W; epilogue: base = b + dis^2*h, h16 = bf16(h) ===

__global__ __launch_bounds__(256) void gemm_h(
    const float* __restrict__ x, const float* __restrict__ W,
    const float* __restrict__ b, const float* __restrict__ dis,
    float* __restrict__ base, unsigned short* __restrict__ h16, int n)
{
    __shared__ float Ws[64 * 64];
    __shared__ float Xs[64 * 68];

    const int t  = threadIdx.x;
    const int r0 = blockIdx.x * 64;
    const int rows = min(64, n - r0);

    {
        const float4* W4 = (const float4*)W;
        float4* Ws4 = (float4*)Ws;
        #pragma unroll
        for (int k = 0; k < 4; ++k) Ws4[t + 256 * k] = W4[t + 256 * k];
    }
    {
        const float4* X4 = (const float4*)(x + (size_t)r0 * DD);
        const int nf4 = rows * 16;
        #pragma unroll
        for (int k = 0; k < 4; ++k) {
            int idx = t + 256 * k;
            float4 v = make_float4(0.f, 0.f, 0.f, 0.f);
            if (idx < nf4) v = X4[idx];
            int row = idx >> 4, c4 = (idx & 15) * 4;
            *(float4*)&Xs[row * 68 + c4] = v;
        }
    }
    __syncthreads();

    const int row0 = (t >> 4) * 4;
    const int col0 = (t & 15) * 4;

    float a[4][4];
    #pragma unroll
    for (int i = 0; i < 4; ++i)
        #pragma unroll
        for (int j = 0; j < 4; ++j) a[i][j] = 0.f;

    #pragma unroll 4
    for (int j = 0; j < 64; ++j) {
        float4 wv = *(const float4*)&Ws[j * 64 + col0];
        float xr[4];
        #pragma unroll
        for (int i = 0; i < 4; ++i) xr[i] = Xs[(row0 + i) * 68 + j];
        #pragma unroll
        for (int i = 0; i < 4; ++i) {
            a[i][0] = fmaf(xr[i], wv.x, a[i][0]);
            a[i][1] = fmaf(xr[i], wv.y, a[i][1]);
            a[i][2] = fmaf(xr[i], wv.z, a[i][2]);
            a[i][3] = fmaf(xr[i], wv.w, a[i][3]);
        }
    }

    float4 bv = *(const float4*)&b[col0];
    #pragma unroll
    for (int i = 0; i < 4; ++i) {
        int r = r0 + row0 + i;
        if (r < n) {
            float di = dis[r];
            float d2 = di * di;
            *(float4*)&base[(size_t)r * DD + col0] =
                make_float4(fmaf(d2, a[i][0], bv.x), fmaf(d2, a[i][1], bv.y),
                            fmaf(d2, a[i][2], bv.z), fmaf(d2, a[i][3], bv.w));
            ushort4 hv;
            hv.x = f2bf(a[i][0]); hv.y = f2bf(a[i][1]);
            hv.z = f2bf(a[i][2]); hv.w = f2bf(a[i][3]);
            *(ushort4*)&h16[(size_t)r * DD + col0] = hv;
        }
    }
}

// ======================= CSR gather (one wave per node, bf16 neighbors) ========

template <bool FINAL>
__global__ __launch_bounds__(256) void gather_csr(
    const unsigned short* __restrict__ h16, const float* __restrict__ base,
    const int* __restrict__ rowptr, const int2* __restrict__ csr,
    const float* __restrict__ prev, float* __restrict__ out)
{
    const int node = __builtin_amdgcn_readfirstlane(
        (blockIdx.x * blockDim.x + threadIdx.x) >> 6);
    const int lane = threadIdx.x & 63;
    if (node >= NN) return;

    float a0 = base[node * DD + lane];
    float a1 = 0.f, a2 = 0.f, a3 = 0.f;

    int j   = rowptr[node];
    int end = rowptr[node + 1];
    for (; j + 3 < end; j += 4) {
        int2 e0 = csr[j], e1 = csr[j + 1], e2 = csr[j + 2], e3 = csr[j + 3];
        a0 = fmaf(__int_as_float(e0.y), bf2f(h16[e0.x * DD + lane]), a0);
        a1 = fmaf(__int_as_float(e1.y), bf2f(h16[e1.x * DD + lane]), a1);
        a2 = fmaf(__int_as_float(e2.y), bf2f(h16[e2.x * DD + lane]), a2);
        a3 = fmaf(__int_as_float(e3.y), bf2f(h16[e3.x * DD + lane]), a3);
    }
    for (; j < end; ++j) {
        int2 e = csr[j];
        a0 = fmaf(__int_as_float(e.y), bf2f(h16[e.x * DD + lane]), a0);
    }

    float v = fmaxf((a0 + a1) + (a2 + a3), 0.f);
    int idx = node * DD + lane;
    if (FINAL) out[idx] = 0.5f * (prev[idx] + v);
    else       out[idx] = v;
}

// ======================= launch =======================

extern "C" void kernel_launch(void* const* d_in, const int* in_sizes, int n_in,
                              void* d_out, int out_size, void* d_ws, size_t ws_size,
                              hipStream_t stream) {
    const float* x   = (const float*)d_in[0];
    const int*   ei  = (const int*)d_in[1];
    const float* ewt = (const float*)d_in[2];
    const float* W1  = (const float*)d_in[3];
    const float* b1  = (const float*)d_in[4];
    const float* W2  = (const float*)d_in[5];
    const float* b2  = (const float*)d_in[6];
    float* out = (float*)d_out;

    const int* srcv = ei;
    const int* dstv = ei + NE;

    // workspace layout in 4B units (d_ws is 8B-aligned):
    //  packed  u64  [100000]         -> 204800 slots
    //  dis     f32  [102400]
    //  rowptr  i32  [102400]
    //  bsums   i32  [1024]
    //  csr     int2 [NE]             -> 2*NE slots (8B-aligned: offset even)
    //  rank    i32  [NE]  } aliased: base f32 [NN*64] overlays rank region
    //  (base extends past rank: region is 6.4M slots)
    //  h16     u16  [NN*64]          -> 3.2M slots
    float* wsf = (float*)d_ws;
    unsigned long long* packed = (unsigned long long*)d_ws;        // 204800
    float* dis    = wsf + 204800;                                  // 102400
    int*   rowptr = (int*)(wsf + 204800 + 102400);                 // 102400
    int*   bsums  = rowptr + 102400;                               // 1024
    int2*  csr    = (int2*)(bsums + 1024);                         // 2*NE
    int*   rank   = (int*)(csr + NE);                              // union w/ base
    float* base   = (float*)rank;                                  // NN*64 (>= NE ok)
    unsigned short* h16 = (unsigned short*)(base + (size_t)NN * DD);

    const int NB_N = (NN + 255) / 256;
    const int NB_E = (NE + 255) / 256;
    const int NB_S = (NN + 511) / 512;       // 196

    // --- norm + CSR (graph shared by both layers) ---
    init_packed<<<NB_N, 256, 0, stream>>>(packed, NN);
    hist64<<<NB_E, 256, 0, stream>>>(dstv, ewt, packed, rank, NE);
    scan_packed<<<NB_S, 512, 0, stream>>>(packed, rowptr, bsums, dis, NN);
    scan_block<<<1, 512, 0, stream>>>(bsums, bsums, NB_S);
    scan_add<<<NB_S, 512, 0, stream>>>(rowptr, bsums, NN);
    reorder_edges<<<NB_E, 256, 0, stream>>>(srcv, dstv, ewt, dis, rowptr, rank,
                                            csr, NE);

    const int GB = (NN * 64) / 256;          // 25000 blocks, one wave per node

    // --- layer 1 (base aliases rank: rank is dead after reorder) ---
    gemm_h<<<(NN + 63) / 64, 256, 0, stream>>>(x, W1, b1, dis, base, h16, NN);
    gather_csr<false><<<GB, 256, 0, stream>>>(h16, base, rowptr, csr, nullptr, out);

    // --- layer 2 (input = x1 in d_out) ---
    gemm_h<<<(NN + 63) / 64, 256, 0, stream>>>(out, W2, b2, dis, base, h16, NN);
    gather_csr<true><<<GB, 256, 0, stream>>>(h16, base, rowptr, csr, out, out);
}

// Round 5
// 276.702 us; speedup vs baseline: 2.6097x; 1.0792x over previous
//
#include <hip/hip_runtime.h>

#define NN 100000
#define NE 1200000
#define DD 64

#define FIX_SCALE 1099511627776.0f   // 2^40
#define FIX_INV   (1.0 / 1099511627776.0)

typedef short bf16x8 __attribute__((ext_vector_type(8)));
typedef float f32x4  __attribute__((ext_vector_type(4)));

static __device__ __forceinline__ unsigned short f2bf(float f) {
    unsigned int u = __float_as_uint(f);
    unsigned int r = (u + 0x7fffu + ((u >> 16) & 1u)) >> 16;   // RNE
    return (unsigned short)r;
}
static __device__ __forceinline__ float bf2f(unsigned short s) {
    return __uint_as_float(((unsigned int)s) << 16);
}

// ======================= packed histogram =======================
// packed[d]: bits[48:63] = count, bits[0:47] = sum(ew) in 2^-40 fixed point.
// Returned old count = edge's rank within its dst segment (atomic-free reorder).

__global__ void init_packed(unsigned long long* __restrict__ packed, int n) {
    int i = blockIdx.x * blockDim.x + threadIdx.x;
    if (i < n) packed[i] = 0ull;
}

__global__ void hist64(const int* __restrict__ dst, const float* __restrict__ ew,
                       unsigned long long* __restrict__ packed,
                       int* __restrict__ rank, int ne) {
    int i = blockIdx.x * blockDim.x + threadIdx.x;
    if (i < ne) {
        int d = dst[i];
        unsigned long long inc =
            (1ull << 48) | (unsigned long long)(ew[i] * FIX_SCALE);
        unsigned long long old = atomicAdd(&packed[d], inc);
        rank[i] = (int)(old >> 48);
    }
}

// ---- scan level 1 fused with dis computation ----

__global__ __launch_bounds__(512) void scan_packed(
    const unsigned long long* __restrict__ packed,
    int* __restrict__ rowptr, int* __restrict__ bsums,
    float* __restrict__ dis, int n)
{
    __shared__ int s[512];
    int t = threadIdx.x;
    int i = blockIdx.x * 512 + t;
    int v = 0;
    if (i < n) {
        unsigned long long p = packed[i];
        v = (int)(p >> 48);
        float deg = 1.0f + (float)((double)(p & ((1ull << 48) - 1)) * FIX_INV);
        dis[i] = rsqrtf(deg);
    }
    s[t] = v;
    __syncthreads();
    for (int off = 1; off < 512; off <<= 1) {
        int add = (t >= off) ? s[t - off] : 0;
        __syncthreads();
        s[t] += add;
        __syncthreads();
    }
    if (i < n) rowptr[i] = s[t] - v;       // exclusive
    if (t == 511) bsums[blockIdx.x] = s[511];
}

__global__ __launch_bounds__(512) void scan_block(const int* __restrict__ in,
                                                  int* __restrict__ out, int n) {
    __shared__ int s[512];
    int t = threadIdx.x;
    int v = (t < n) ? in[t] : 0;
    s[t] = v;
    __syncthreads();
    for (int off = 1; off < 512; off <<= 1) {
        int add = (t >= off) ? s[t - off] : 0;
        __syncthreads();
        s[t] += add;
        __syncthreads();
    }
    if (t < n) out[t] = s[t] - v;
}

__global__ __launch_bounds__(512) void scan_add(int* __restrict__ rowptr,
                                                const int* __restrict__ bsums, int n) {
    int i = blockIdx.x * 512 + threadIdx.x;
    if (i < n) rowptr[i] += bsums[blockIdx.x];
    if (i == 0) rowptr[n] = NE;            // sentinel
}

// ---- atomic-free reorder: csr[rowptr[d] + rank[e]] = {src, norm} ----

__global__ void reorder_edges(const int* __restrict__ src, const int* __restrict__ dst,
                              const float* __restrict__ ew, const float* __restrict__ dis,
                              const int* __restrict__ rowptr, const int* __restrict__ rank,
                              int2* __restrict__ csr, int ne) {
    int e = blockIdx.x * blockDim.x + threadIdx.x;
    if (e < ne) {
        int s = src[e], d = dst[e];
        int pos = rowptr[d] + rank[e];
        float norm = dis[s] * ew[e] * dis[d];
        csr[pos] = make_int2(s, __float_as_int(norm));
    }
}

// ======================= W -> bf16 transposed (once) =======================
// Wt[col][k] = bf16(W[k][col]); block 0 -> W1, block 1 -> W2.

__global__ __launch_bounds__(256) void prep_w(
    const float* __restrict__ W1, const float* __restrict__ W2,
    unsigned short* __restrict__ Wt1, unsigned short* __restrict__ Wt2)
{
    const float* W = blockIdx.x ? W2 : W1;
    unsigned short* Wt = blockIdx.x ? Wt2 : Wt1;
    int t = threadIdx.x;
    int col = t >> 2, k0 = (t & 3) * 16;
    #pragma unroll
    for (int i = 0; i < 16; ++i)
        Wt[col * 64 + k0 + i] = f2bf(W[(k0 + i) * 64 + col]);
}

// ======================= MFMA GEMM: h = x@W (bf16 in, fp32 acc) ============
// 256 threads = 4 waves; 64-row tile; each wave: 16 rows x 64 cols.
// mfma_f32_16x16x32_bf16: A[m=lane&15][k=quad*8+j], B[n=lane&15][k=quad*8+j],
// D[row=quad*4+reg][col=lane&15]. LDS stride 72 (2-way bank alias = free).
// Epilogue: h16 = bf16(h), base = b + dis^2 * h (fp32).

__global__ __launch_bounds__(256) void gemm_mfma(
    const float* __restrict__ x, const unsigned short* __restrict__ Wt,
    const float* __restrict__ b, const float* __restrict__ dis,
    float* __restrict__ base, unsigned short* __restrict__ h16, int n)
{
    __shared__ unsigned short Xs[64 * 72];
    __shared__ unsigned short Ws[64 * 72];

    const int t  = threadIdx.x;
    const int r0 = blockIdx.x * 64;

    // stage Wt (already [col][k] bf16): 16 ushorts per thread
    {
        int col = t >> 2, seg = (t & 3) * 16;
        const uint4* p = (const uint4*)(Wt + col * 64 + seg);
        uint4 a0 = p[0], a1 = p[1];
        *(uint4*)&Ws[col * 72 + seg]     = a0;
        *(uint4*)&Ws[col * 72 + seg + 8] = a1;
    }
    // stage X: fp32 -> bf16, 16 floats per thread
    {
        int row = t >> 2, seg = (t & 3) * 16;
        int gr = r0 + row;
        float4 v0 = {0,0,0,0}, v1 = v0, v2 = v0, v3 = v0;
        if (gr < n) {
            const float4* p = (const float4*)(x + (size_t)gr * DD + seg);
            v0 = p[0]; v1 = p[1]; v2 = p[2]; v3 = p[3];
        }
        ushort4 h0 = { f2bf(v0.x), f2bf(v0.y), f2bf(v0.z), f2bf(v0.w) };
        ushort4 h1 = { f2bf(v1.x), f2bf(v1.y), f2bf(v1.z), f2bf(v1.w) };
        ushort4 h2 = { f2bf(v2.x), f2bf(v2.y), f2bf(v2.z), f2bf(v2.w) };
        ushort4 h3 = { f2bf(v3.x), f2bf(v3.y), f2bf(v3.z), f2bf(v3.w) };
        *(ushort4*)&Xs[row * 72 + seg]      = h0;
        *(ushort4*)&Xs[row * 72 + seg + 4]  = h1;
        *(ushort4*)&Xs[row * 72 + seg + 8]  = h2;
        *(ushort4*)&Xs[row * 72 + seg + 12] = h3;
    }
    __syncthreads();

    const int wv = t >> 6;
    const int ln = t & 63;
    const int m  = ln & 15;
    const int q  = ln >> 4;
    const int arow = wv * 16 + m;

    bf16x8 a0 = *(const bf16x8*)&Xs[arow * 72 + q * 8];
    bf16x8 a1 = *(const bf16x8*)&Xs[arow * 72 + 32 + q * 8];

    f32x4 acc[4];
    #pragma unroll
    for (int c = 0; c < 4; ++c) {
        bf16x8 b0 = *(const bf16x8*)&Ws[(c * 16 + m) * 72 + q * 8];
        bf16x8 b1 = *(const bf16x8*)&Ws[(c * 16 + m) * 72 + 32 + q * 8];
        f32x4 z = {0.f, 0.f, 0.f, 0.f};
        z = __builtin_amdgcn_mfma_f32_16x16x32_bf16(a0, b0, z, 0, 0, 0);
        z = __builtin_amdgcn_mfma_f32_16x16x32_bf16(a1, b1, z, 0, 0, 0);
        acc[c] = z;
    }

    #pragma unroll
    for (int r = 0; r < 4; ++r) {
        int grow = r0 + wv * 16 + q * 4 + r;
        if (grow < n) {
            float di = dis[grow];
            float d2 = di * di;
            #pragma unroll
            for (int c = 0; c < 4; ++c) {
                float hv = acc[c][r];
                int col = c * 16 + m;
                h16[(size_t)grow * DD + col]  = f2bf(hv);
                base[(size_t)grow * DD + col] = fmaf(d2, hv, b[col]);
            }
        }
    }
}

// ======================= CSR gather (one wave per node, bf16 neighbors) ========

template <bool FINAL>
__global__ __launch_bounds__(256) void gather_csr(
    const unsigned short* __restrict__ h16, const float* __restrict__ base,
    const int* __restrict__ rowptr, const int2* __restrict__ csr,
    const float* __restrict__ prev, float* __restrict__ out)
{
    const int node = __builtin_amdgcn_readfirstlane(
        (blockIdx.x * blockDim.x + threadIdx.x) >> 6);
    const int lane = threadIdx.x & 63;
    if (node >= NN) return;

    float a0 = base[node * DD + lane];
    float a1 = 0.f, a2 = 0.f, a3 = 0.f;

    int j   = rowptr[node];
    int end = rowptr[node + 1];
    for (; j + 7 < end; j += 8) {
        int2 e0 = csr[j],     e1 = csr[j + 1], e2 = csr[j + 2], e3 = csr[j + 3];
        int2 e4 = csr[j + 4], e5 = csr[j + 5], e6 = csr[j + 6], e7 = csr[j + 7];
        a0 = fmaf(__int_as_float(e0.y), bf2f(h16[e0.x * DD + lane]), a0);
        a1 = fmaf(__int_as_float(e1.y), bf2f(h16[e1.x * DD + lane]), a1);
        a2 = fmaf(__int_as_float(e2.y), bf2f(h16[e2.x * DD + lane]), a2);
        a3 = fmaf(__int_as_float(e3.y), bf2f(h16[e3.x * DD + lane]), a3);
        a0 = fmaf(__int_as_float(e4.y), bf2f(h16[e4.x * DD + lane]), a0);
        a1 = fmaf(__int_as_float(e5.y), bf2f(h16[e5.x * DD + lane]), a1);
        a2 = fmaf(__int_as_float(e6.y), bf2f(h16[e6.x * DD + lane]), a2);
        a3 = fmaf(__int_as_float(e7.y), bf2f(h16[e7.x * DD + lane]), a3);
    }
    for (; j + 1 < end; j += 2) {
        int2 ea = csr[j], eb = csr[j + 1];
        a0 = fmaf(__int_as_float(ea.y), bf2f(h16[ea.x * DD + lane]), a0);
        a1 = fmaf(__int_as_float(eb.y), bf2f(h16[eb.x * DD + lane]), a1);
    }
    if (j < end) {
        int2 e = csr[j];
        a0 = fmaf(__int_as_float(e.y), bf2f(h16[e.x * DD + lane]), a0);
    }

    float v = fmaxf((a0 + a1) + (a2 + a3), 0.f);
    int idx = node * DD + lane;
    if (FINAL) out[idx] = 0.5f * (prev[idx] + v);
    else       out[idx] = v;
}

// ======================= launch =======================

extern "C" void kernel_launch(void* const* d_in, const int* in_sizes, int n_in,
                              void* d_out, int out_size, void* d_ws, size_t ws_size,
                              hipStream_t stream) {
    const float* x   = (const float*)d_in[0];
    const int*   ei  = (const int*)d_in[1];
    const float* ewt = (const float*)d_in[2];
    const float* W1  = (const float*)d_in[3];
    const float* b1  = (const float*)d_in[4];
    const float* W2  = (const float*)d_in[5];
    const float* b2  = (const float*)d_in[6];
    float* out = (float*)d_out;

    const int* srcv = ei;
    const int* dstv = ei + NE;

    // workspace layout in 4B slots (d_ws 8B-aligned); ~49.7 MB total:
    float* wsf = (float*)d_ws;
    unsigned long long* packed = (unsigned long long*)d_ws;          // 204800 slots
    float* dis    = wsf + 204800;                                    // 102400
    int*   rowptr = (int*)(wsf + 307200);                            // 102400
    int*   bsums  = rowptr + 102400;                                 // 1024
    unsigned short* Wt1 = (unsigned short*)(bsums + 1024);           // 2048 slots
    unsigned short* Wt2 = Wt1 + 4096;                                // 2048 slots
    int2*  csr    = (int2*)(Wt2 + 4096);                             // 2*NE slots (8B-aligned)
    int*   rank   = (int*)(csr + NE);                                // union w/ base
    float* base   = (float*)rank;                                    // NN*64 fp32
    unsigned short* h16 = (unsigned short*)(base + (size_t)NN * DD); // NN*64 bf16

    const int NB_N = (NN + 255) / 256;
    const int NB_E = (NE + 255) / 256;
    const int NB_S = (NN + 511) / 512;       // 196

    // --- norm + CSR (graph shared by both layers) ---
    init_packed<<<NB_N, 256, 0, stream>>>(packed, NN);
    hist64<<<NB_E, 256, 0, stream>>>(dstv, ewt, packed, rank, NE);
    prep_w<<<2, 256, 0, stream>>>(W1, W2, Wt1, Wt2);
    scan_packed<<<NB_S, 512, 0, stream>>>(packed, rowptr, bsums, dis, NN);
    scan_block<<<1, 512, 0, stream>>>(bsums, bsums, NB_S);
    scan_add<<<NB_S, 512, 0, stream>>>(rowptr, bsums, NN);
    reorder_edges<<<NB_E, 256, 0, stream>>>(srcv, dstv, ewt, dis, rowptr, rank,
                                            csr, NE);

    const int GB = (NN * 64) / 256;          // 25000 blocks, one wave per node

    // --- layer 1 (base aliases rank: rank dead after reorder) ---
    gemm_mfma<<<(NN + 63) / 64, 256, 0, stream>>>(x, Wt1, b1, dis, base, h16, NN);
    gather_csr<false><<<GB, 256, 0, stream>>>(h16, base, rowptr, csr, nullptr, out);

    // --- layer 2 (input = x1 in d_out) ---
    gemm_mfma<<<(NN + 63) / 64, 256, 0, stream>>>(out, Wt2, b2, dis, base, h16, NN);
    gather_csr<true><<<GB, 256, 0, stream>>>(h16, base, rowptr, csr, out, out);
}